// Round 1
// baseline (512.293 us; speedup 1.0000x reference)
//
#include <hip/hip_runtime.h>

#define S   56
#define CD  64
#define C0  128
#define NB  16
#define EPSF 1e-5f

// ---------------------------------------------------------------------------
// conv_down (128->64) + BN + ReLU.  One block per (b,h): stage x[b,:,h,:] in
// LDS (128x56), each thread computes outputs (o,w) with a 128-MAC dot.
// ---------------------------------------------------------------------------
__global__ __launch_bounds__(256)
void conv_down_kernel(const float* __restrict__ x, const float* __restrict__ w,
                      const float* __restrict__ bn, float* __restrict__ out)
{
    int bh = blockIdx.x;
    int b = bh / S, h = bh - (bh / S) * S;
    __shared__ float xs[C0][S];
    for (int idx = threadIdx.x; idx < C0 * S; idx += 256) {
        int c = idx / S, wv = idx - (idx / S) * S;
        xs[c][wv] = x[(((size_t)b * C0 + c) * S + h) * S + wv];
    }
    __syncthreads();
    for (int idx = threadIdx.x; idx < CD * S; idx += 256) {
        int o = idx / S, wv = idx - (idx / S) * S;
        const float* wr = w + o * C0;
        float acc = 0.f;
        #pragma unroll 8
        for (int c = 0; c < C0; ++c) acc += wr[c] * xs[c][wv];
        float sc = bn[o] * rsqrtf(bn[3 * CD + o] + EPSF);
        float bi = bn[CD + o] - sc * bn[2 * CD + o];
        float v = sc * acc + bi;
        out[(((size_t)b * CD + o) * S + h) * S + wv] = v > 0.f ? v : 0.f;
    }
}

// ---------------------------------------------------------------------------
// Axial attention.  ORIENT=0: attend along H (p = w); ORIENT=1: attend along
// W (p = h).  One block per (n, p, g).  All fp32 in LDS.
// ---------------------------------------------------------------------------
template <int ORIENT>
__device__ __forceinline__ size_t xidx(int n, int c, int p, int l)
{
    if (ORIENT == 0) return (((size_t)n * CD + c) * S + l) * S + p;
    else             return (((size_t)n * CD + c) * S + p) * S + l;
}

template <int ORIENT>
__global__ __launch_bounds__(256)
void attn_kernel(const float* __restrict__ xin,
                 const float* __restrict__ qkvw,   // 128 x 64
                 const float* __restrict__ bnqkv,  // 4 x 128
                 const float* __restrict__ bnsim,  // 4 x 24
                 const float* __restrict__ bnout,  // 4 x 128
                 const float* __restrict__ rel,    // 16 x 111
                 float* __restrict__ xout)
{
    const int tid = threadIdx.x;
    int bid = blockIdx.x;
    int g  = bid & 7;
    int np = bid >> 3;
    int n  = np / S;
    int p  = np - n * S;

    __shared__ float sx[CD][S];        // input tile (c, l)
    __shared__ float sqkv[16][S + 1];  // rows 0-3 q, 4-7 k, 8-15 v
    __shared__ float ssim[S][S + 1];
    __shared__ float srel[16][112];
    __shared__ float sZ[S];

    for (int idx = tid; idx < CD * S; idx += 256) {
        int c = idx / S, l = idx - (idx / S) * S;
        sx[c][l] = xin[xidx<ORIENT>(n, c, p, l)];
    }
    for (int idx = tid; idx < 16 * 111; idx += 256) {
        int r = idx / 111, d = idx - (idx / 111) * 111;
        srel[r][d] = rel[idx];
    }
    __syncthreads();

    // qkv for this group's 16 channels, with BN folded in
    for (int idx = tid; idx < 16 * S; idx += 256) {
        int r = idx / S, l = idx - (idx / S) * S;
        int oc = g * 16 + r;
        const float* wr = qkvw + oc * CD;
        float acc = 0.f;
        #pragma unroll 8
        for (int c = 0; c < CD; ++c) acc += wr[c] * sx[c][l];
        float sc = bnqkv[oc] * rsqrtf(bnqkv[3 * 128 + oc] + EPSF);
        float bi = bnqkv[128 + oc] - sc * bnqkv[2 * 128 + oc];
        sqkv[r][l] = sc * acc + bi;
    }
    __syncthreads();

    // BN(sim) per-channel affine for the 3 terms (channels g, 8+g, 16+g)
    float s_qk = bnsim[g]          * rsqrtf(bnsim[72 + g] + EPSF);
    float b_qk = bnsim[24 + g]     - s_qk * bnsim[48 + g];
    float s_qr = bnsim[8 + g]      * rsqrtf(bnsim[72 + 8 + g] + EPSF);
    float b_qr = bnsim[24 + 8 + g] - s_qr * bnsim[48 + 8 + g];
    float s_kr = bnsim[16 + g]     * rsqrtf(bnsim[72 + 16 + g] + EPSF);
    float b_kr = bnsim[24 + 16 + g]- s_kr * bnsim[48 + 16 + g];

    for (int idx = tid; idx < S * S; idx += 256) {
        int i = idx / S, j = idx - (idx / S) * S;
        float qk = 0.f, qr = 0.f, kr = 0.f;
        #pragma unroll
        for (int c = 0; c < 4; ++c) {
            float qv = sqkv[c][i];
            float kv = sqkv[4 + c][j];
            qk += qv * kv;
            qr += qv * srel[c][i - j + 55];
            kr += kv * srel[4 + c][j - i + 55];
        }
        ssim[i][j] = s_qk * qk + b_qk + s_qr * qr + b_qr + s_kr * kr + b_kr;
    }
    __syncthreads();

    // row softmax: store unnormalized exp, remember Z (divide later)
    if (tid < S) {
        float m = -1e30f;
        for (int j = 0; j < S; ++j) m = fmaxf(m, ssim[tid][j]);
        float z = 0.f;
        for (int j = 0; j < S; ++j) {
            float e = __expf(ssim[tid][j] - m);
            ssim[tid][j] = e;
            z += e;
        }
        sZ[tid] = z;
    }
    __syncthreads();

    // sv + sve, BN(out) affine on both, sum, write
    for (int idx = tid; idx < 8 * S; idx += 256) {
        int c = idx / S, i = idx - (idx / S) * S;
        float av = 0.f, ae = 0.f;
        #pragma unroll 8
        for (int j = 0; j < S; ++j) {
            float sm = ssim[i][j];
            av += sm * sqkv[8 + c][j];
            ae += sm * srel[8 + c][i - j + 55];
        }
        float invZ = 1.f / sZ[i];
        av *= invZ; ae *= invZ;
        int oc0 = g * 16 + c * 2, oc1 = oc0 + 1;
        float s0 = bnout[oc0] * rsqrtf(bnout[3 * 128 + oc0] + EPSF);
        float b0 = bnout[128 + oc0] - s0 * bnout[2 * 128 + oc0];
        float s1 = bnout[oc1] * rsqrtf(bnout[3 * 128 + oc1] + EPSF);
        float b1 = bnout[128 + oc1] - s1 * bnout[2 * 128 + oc1];
        xout[xidx<ORIENT>(n, g * 8 + c, p, i)] = (s0 * av + b0) + (s1 * ae + b1);
    }
}

// ---------------------------------------------------------------------------
// ReLU + conv_up (64->128) + BN + residual-add + ReLU
// ---------------------------------------------------------------------------
__global__ __launch_bounds__(256)
void conv_up_kernel(const float* __restrict__ xin, const float* __restrict__ w,
                    const float* __restrict__ bn, const float* __restrict__ xres,
                    float* __restrict__ out)
{
    int bh = blockIdx.x;
    int b = bh / S, h = bh - (bh / S) * S;
    __shared__ float xs[CD][S];
    for (int idx = threadIdx.x; idx < CD * S; idx += 256) {
        int c = idx / S, wv = idx - (idx / S) * S;
        float v = xin[(((size_t)b * CD + c) * S + h) * S + wv];
        xs[c][wv] = v > 0.f ? v : 0.f;
    }
    __syncthreads();
    for (int idx = threadIdx.x; idx < C0 * S; idx += 256) {
        int o = idx / S, wv = idx - (idx / S) * S;
        const float* wr = w + o * CD;
        float acc = 0.f;
        #pragma unroll 8
        for (int c = 0; c < CD; ++c) acc += wr[c] * xs[c][wv];
        float sc = bn[o] * rsqrtf(bn[3 * C0 + o] + EPSF);
        float bi = bn[C0 + o] - sc * bn[2 * C0 + o];
        size_t oi = (((size_t)b * C0 + o) * S + h) * S + wv;
        float v = sc * acc + bi + xres[oi];
        out[oi] = v > 0.f ? v : 0.f;
    }
}

extern "C" void kernel_launch(void* const* d_in, const int* in_sizes, int n_in,
                              void* d_out, int out_size, void* d_ws, size_t ws_size,
                              hipStream_t stream)
{
    const float* x      = (const float*)d_in[0];
    const float* cdw    = (const float*)d_in[1];
    const float* bn1    = (const float*)d_in[2];
    const float* hqkv   = (const float*)d_in[3];
    const float* hbnqkv = (const float*)d_in[4];
    const float* hbnsim = (const float*)d_in[5];
    const float* hbnout = (const float*)d_in[6];
    const float* hrel   = (const float*)d_in[7];
    const float* wqkv   = (const float*)d_in[8];
    const float* wbnqkv = (const float*)d_in[9];
    const float* wbnsim = (const float*)d_in[10];
    const float* wbnout = (const float*)d_in[11];
    const float* wrel   = (const float*)d_in[12];
    const float* cuw    = (const float*)d_in[13];
    const float* bn2    = (const float*)d_in[14];

    float* buf0 = (float*)d_ws;
    float* buf1 = buf0 + (size_t)NB * CD * S * S;

    conv_down_kernel<<<NB * S, 256, 0, stream>>>(x, cdw, bn1, buf0);
    attn_kernel<0><<<NB * S * 8, 256, 0, stream>>>(buf0, hqkv, hbnqkv, hbnsim, hbnout, hrel, buf1);
    attn_kernel<1><<<NB * S * 8, 256, 0, stream>>>(buf1, wqkv, wbnqkv, wbnsim, wbnout, wrel, buf0);
    conv_up_kernel<<<NB * S, 256, 0, stream>>>(buf0, cuw, bn2, x, (float*)d_out);
}

// Round 2
// 396.100 us; speedup vs baseline: 1.2933x; 1.2933x over previous
//
#include <hip/hip_runtime.h>

#define S    56
#define SS   3136        // 56*56
#define CD   64
#define C0   128
#define NB   16
#define EPSF 1e-5f

// ---------------------------------------------------------------------------
// conv_down (128->64) + BN + ReLU.  Block per (b,h).  Writes TRANSPOSED
// layout [b, c, w, h] so attention-H and the qkv GEMM read contiguously.
// ---------------------------------------------------------------------------
__global__ __launch_bounds__(256)
void conv_down_kernel(const float* __restrict__ x, const float* __restrict__ w,
                      const float* __restrict__ bn, float* __restrict__ out)
{
    int bh = blockIdx.x;
    int b = bh / S, h = bh - (bh / S) * S;
    __shared__ float xs[C0][S];
    for (int idx = threadIdx.x; idx < C0 * S; idx += 256) {
        int c = idx / S, wv = idx - (idx / S) * S;
        xs[c][wv] = x[(((size_t)b * C0 + c) * S + h) * S + wv];
    }
    __syncthreads();
    for (int idx = threadIdx.x; idx < CD * S; idx += 256) {
        int o = idx / S, wv = idx - (idx / S) * S;
        const float* wr = w + o * C0;
        float acc = 0.f;
        #pragma unroll 8
        for (int c = 0; c < C0; ++c) acc += wr[c] * xs[c][wv];
        float sc = bn[o] * rsqrtf(bn[3 * CD + o] + EPSF);
        float bi = bn[CD + o] - sc * bn[2 * CD + o];
        float v = sc * acc + bi;
        // transposed write: [b][o][wv][h]
        out[(((size_t)b * CD + o) * S + wv) * S + h] = v > 0.f ? v : 0.f;
    }
}

// ---------------------------------------------------------------------------
// qkv projection GEMM: out[n,o,m] = BN( sum_c w[o,c] * xin[n,c,m] ),
// o=0..127, m=0..3135 (contiguous in both xin and out).
// Block: (n, m-tile of 64).  Thread tile 8(o) x 4(m).
// ---------------------------------------------------------------------------
__global__ __launch_bounds__(256)
void qkv_gemm(const float* __restrict__ xin, const float* __restrict__ w,
              const float* __restrict__ bn, float* __restrict__ out)
{
    __shared__ float wT[64][132];   // [c][o]
    __shared__ float xs[64][68];    // [c][mm]
    int tid = threadIdx.x;
    int n = blockIdx.x / 49, mt = blockIdx.x - (blockIdx.x / 49) * 49;
    int m0 = mt * 64;
    const float* xb = xin + (size_t)n * (CD * SS) + m0;

    for (int idx = tid; idx < 128 * 64; idx += 256) {
        int o = idx >> 6, c = idx & 63;
        wT[c][o] = w[idx];
    }
    for (int idx = tid; idx < 64 * 64; idx += 256) {
        int c = idx >> 6, mm = idx & 63;
        xs[c][mm] = xb[(size_t)c * SS + mm];
    }
    __syncthreads();

    int ty = tid >> 4, tx = tid & 15;
    float acc[8][4];
    #pragma unroll
    for (int r = 0; r < 8; ++r)
        #pragma unroll
        for (int x4 = 0; x4 < 4; ++x4) acc[r][x4] = 0.f;

    #pragma unroll 8
    for (int c = 0; c < 64; ++c) {
        float4 w0 = *(const float4*)&wT[c][ty * 8];
        float4 w1 = *(const float4*)&wT[c][ty * 8 + 4];
        float4 xv = *(const float4*)&xs[c][tx * 4];
        float wr[8] = {w0.x, w0.y, w0.z, w0.w, w1.x, w1.y, w1.z, w1.w};
        float xr[4] = {xv.x, xv.y, xv.z, xv.w};
        #pragma unroll
        for (int r = 0; r < 8; ++r)
            #pragma unroll
            for (int x4 = 0; x4 < 4; ++x4) acc[r][x4] += wr[r] * xr[x4];
    }

    float* ob = out + (size_t)n * (C0 * SS) + m0 + tx * 4;
    #pragma unroll
    for (int r = 0; r < 8; ++r) {
        int o = ty * 8 + r;
        float sc = bn[o] * rsqrtf(bn[384 + o] + EPSF);
        float bi = bn[128 + o] - sc * bn[256 + o];
        float4 res;
        res.x = sc * acc[r][0] + bi;
        res.y = sc * acc[r][1] + bi;
        res.z = sc * acc[r][2] + bi;
        res.w = sc * acc[r][3] + bi;
        *(float4*)&ob[(size_t)o * SS] = res;
    }
}

// ---------------------------------------------------------------------------
// Attention core.  Input qkv: [n][128ch][56p][56l] (BN already applied).
// One block per (n,p), all 8 groups processed sequentially.
// ORIENT only affects the output write index:
//   ORIENT=0 (height attn, p=w, l=h): write [b][c][l][p]  (std layout)
//   ORIENT=1 (width  attn, p=h, l=w): write [b][c][p][l]  (std layout)
// ---------------------------------------------------------------------------
template <int ORIENT>
__global__ __launch_bounds__(256)
void attn_core(const float* __restrict__ qkv,
               const float* __restrict__ bnsim,  // 4 x 24
               const float* __restrict__ bnout,  // 4 x 128
               const float* __restrict__ rel,    // 16 x 111
               float* __restrict__ xout)
{
    __shared__ float sq[128][58];
    __shared__ float ssim[S][58];
    __shared__ float srel[16][112];
    __shared__ float sInv[S];

    int tid = threadIdx.x;
    int n = blockIdx.x / S, p = blockIdx.x - (blockIdx.x / S) * S;
    const float* base = qkv + (size_t)n * (C0 * SS) + p * S;

    for (int idx = tid; idx < C0 * S; idx += 256) {
        int ch = idx / S, l = idx - (idx / S) * S;
        sq[ch][l] = base[(size_t)ch * SS + l];
    }
    for (int idx = tid; idx < 16 * 111; idx += 256) {
        int r = idx / 111, d = idx - (idx / 111) * 111;
        srel[r][d] = rel[idx];
    }
    __syncthreads();

    for (int g = 0; g < 8; ++g) {
        const int cb = g * 16;
        float s_qk = bnsim[g]          * rsqrtf(bnsim[72 + g] + EPSF);
        float s_qr = bnsim[8 + g]      * rsqrtf(bnsim[72 + 8 + g] + EPSF);
        float s_kr = bnsim[16 + g]     * rsqrtf(bnsim[72 + 16 + g] + EPSF);
        float bsum = (bnsim[24 + g]      - s_qk * bnsim[48 + g])
                   + (bnsim[24 + 8 + g]  - s_qr * bnsim[48 + 8 + g])
                   + (bnsim[24 + 16 + g] - s_kr * bnsim[48 + 16 + g]);

        // ---- sim: items (i, j-pair), 56*28 = 1568
        for (int idx = tid; idx < S * 28; idx += 256) {
            int i = idx / 28, jp = idx - (idx / 28) * 28;
            int j = jp << 1;
            float q0 = sq[cb + 0][i], q1 = sq[cb + 1][i],
                  q2 = sq[cb + 2][i], q3 = sq[cb + 3][i];
            float2 k0 = *(const float2*)&sq[cb + 4][j];
            float2 k1 = *(const float2*)&sq[cb + 5][j];
            float2 k2 = *(const float2*)&sq[cb + 6][j];
            float2 k3 = *(const float2*)&sq[cb + 7][j];
            float qk0 = q0 * k0.x + q1 * k1.x + q2 * k2.x + q3 * k3.x;
            float qk1 = q0 * k0.y + q1 * k1.y + q2 * k2.y + q3 * k3.y;
            int dq = i - j + 55;           // entry j ; entry j+1 uses dq-1
            float qr0 = q0 * srel[0][dq]     + q1 * srel[1][dq]
                      + q2 * srel[2][dq]     + q3 * srel[3][dq];
            float qr1 = q0 * srel[0][dq - 1] + q1 * srel[1][dq - 1]
                      + q2 * srel[2][dq - 1] + q3 * srel[3][dq - 1];
            int dk = j - i + 55;           // entry j ; entry j+1 uses dk+1
            float kr0 = k0.x * srel[4][dk]     + k1.x * srel[5][dk]
                      + k2.x * srel[6][dk]     + k3.x * srel[7][dk];
            float kr1 = k0.y * srel[4][dk + 1] + k1.y * srel[5][dk + 1]
                      + k2.y * srel[6][dk + 1] + k3.y * srel[7][dk + 1];
            ssim[i][j]     = s_qk * qk0 + s_qr * qr0 + s_kr * kr0 + bsum;
            ssim[i][j + 1] = s_qk * qk1 + s_qr * qr1 + s_kr * kr1 + bsum;
        }
        __syncthreads();

        // ---- softmax: 4-lane team per row, store unnormalized exp + 1/Z
        if (tid < 224) {
            int t = tid >> 2, q4 = tid & 3;
            float m = -3e38f;
            #pragma unroll
            for (int k = 0; k < 14; ++k) m = fmaxf(m, ssim[t][q4 + 4 * k]);
            m = fmaxf(m, __shfl_xor(m, 1));
            m = fmaxf(m, __shfl_xor(m, 2));
            float z = 0.f;
            #pragma unroll
            for (int k = 0; k < 14; ++k) {
                float e = __expf(ssim[t][q4 + 4 * k] - m);
                ssim[t][q4 + 4 * k] = e;
                z += e;
            }
            z += __shfl_xor(z, 1);
            z += __shfl_xor(z, 2);
            if (q4 == 0) sInv[t] = 1.f / z;
        }
        __syncthreads();

        // ---- sv + sve + BN(out) + pair-sum; items (cpair, i): 4*56 = 224
        if (tid < 224) {
            int cp = tid / S, i = tid - (tid / S) * S;
            int c0 = cp * 2, c1 = c0 + 1;
            float av0 = 0.f, ae0 = 0.f, av1 = 0.f, ae1 = 0.f;
            #pragma unroll 4
            for (int jp = 0; jp < 28; ++jp) {
                int j = jp << 1;
                float2 sm  = *(const float2*)&ssim[i][j];
                float2 vv0 = *(const float2*)&sq[cb + 8 + c0][j];
                float2 vv1 = *(const float2*)&sq[cb + 8 + c1][j];
                int d = i - j + 55;
                av0 += sm.x * vv0.x + sm.y * vv0.y;
                av1 += sm.x * vv1.x + sm.y * vv1.y;
                ae0 += sm.x * srel[8 + c0][d] + sm.y * srel[8 + c0][d - 1];
                ae1 += sm.x * srel[8 + c1][d] + sm.y * srel[8 + c1][d - 1];
            }
            float inv = sInv[i];
            av0 *= inv; ae0 *= inv; av1 *= inv; ae1 *= inv;

            int oa = cb + c0 * 2;           // sv BN ch for c0
            float sa = bnout[oa]     * rsqrtf(bnout[384 + oa] + EPSF);
            float ba = bnout[128 + oa] - sa * bnout[256 + oa];
            float se = bnout[oa + 1] * rsqrtf(bnout[384 + oa + 1] + EPSF);
            float be = bnout[128 + oa + 1] - se * bnout[256 + oa + 1];
            float r0 = (sa * av0 + ba) + (se * ae0 + be);

            int ob = cb + c1 * 2;
            float sb = bnout[ob]     * rsqrtf(bnout[384 + ob] + EPSF);
            float bb = bnout[128 + ob] - sb * bnout[256 + ob];
            float sf = bnout[ob + 1] * rsqrtf(bnout[384 + ob + 1] + EPSF);
            float bf = bnout[128 + ob + 1] - sf * bnout[256 + ob + 1];
            float r1 = (sb * av1 + bb) + (sf * ae1 + bf);

            int ch0 = g * 8 + c0, ch1 = g * 8 + c1;
            if (ORIENT == 0) {
                xout[(((size_t)n * CD + ch0) * S + i) * S + p] = r0;
                xout[(((size_t)n * CD + ch1) * S + i) * S + p] = r1;
            } else {
                xout[(((size_t)n * CD + ch0) * S + p) * S + i] = r0;
                xout[(((size_t)n * CD + ch1) * S + p) * S + i] = r1;
            }
        }
        __syncthreads();
    }
}

// ---------------------------------------------------------------------------
// ReLU + conv_up (64->128) + BN + residual-add + ReLU
// ---------------------------------------------------------------------------
__global__ __launch_bounds__(256)
void conv_up_kernel(const float* __restrict__ xin, const float* __restrict__ w,
                    const float* __restrict__ bn, const float* __restrict__ xres,
                    float* __restrict__ out)
{
    int bh = blockIdx.x;
    int b = bh / S, h = bh - (bh / S) * S;
    __shared__ float xs[CD][S];
    for (int idx = threadIdx.x; idx < CD * S; idx += 256) {
        int c = idx / S, wv = idx - (idx / S) * S;
        float v = xin[(((size_t)b * CD + c) * S + h) * S + wv];
        xs[c][wv] = v > 0.f ? v : 0.f;
    }
    __syncthreads();
    for (int idx = threadIdx.x; idx < C0 * S; idx += 256) {
        int o = idx / S, wv = idx - (idx / S) * S;
        const float* wr = w + o * CD;
        float acc = 0.f;
        #pragma unroll 8
        for (int c = 0; c < CD; ++c) acc += wr[c] * xs[c][wv];
        float sc = bn[o] * rsqrtf(bn[3 * C0 + o] + EPSF);
        float bi = bn[C0 + o] - sc * bn[2 * C0 + o];
        size_t oi = (((size_t)b * C0 + o) * S + h) * S + wv;
        float v = sc * acc + bi + xres[oi];
        out[oi] = v > 0.f ? v : 0.f;
    }
}

extern "C" void kernel_launch(void* const* d_in, const int* in_sizes, int n_in,
                              void* d_out, int out_size, void* d_ws, size_t ws_size,
                              hipStream_t stream)
{
    const float* x      = (const float*)d_in[0];
    const float* cdw    = (const float*)d_in[1];
    const float* bn1    = (const float*)d_in[2];
    const float* hqkv   = (const float*)d_in[3];
    const float* hbnqkv = (const float*)d_in[4];
    const float* hbnsim = (const float*)d_in[5];
    const float* hbnout = (const float*)d_in[6];
    const float* hrel   = (const float*)d_in[7];
    const float* wqkv   = (const float*)d_in[8];
    const float* wbnqkv = (const float*)d_in[9];
    const float* wbnsim = (const float*)d_in[10];
    const float* wbnout = (const float*)d_in[11];
    const float* wrel   = (const float*)d_in[12];
    const float* cuw    = (const float*)d_in[13];
    const float* bn2    = (const float*)d_in[14];

    float* bufT = (float*)d_ws;                 // 16*64*3136  = 3,211,264 f
    float* qbuf = bufT + (size_t)NB * CD * SS;  // 16*128*3136 = 6,422,528 f
    float* abuf = qbuf + (size_t)NB * C0 * SS;  // 16*64*3136  = 3,211,264 f

    // 1. conv_down -> bufT in [b,c,w,h]
    conv_down_kernel<<<NB * S, 256, 0, stream>>>(x, cdw, bn1, bufT);
    // 2. qkv GEMM (H-attn)  bufT -> qbuf  [n,128,(w,h)]
    qkv_gemm<<<NB * 49, 256, 0, stream>>>(bufT, hqkv, hbnqkv, qbuf);
    // 3. attn core H: block per (n, p=w); writes abuf [b,c,h,w]
    attn_core<0><<<NB * S, 256, 0, stream>>>(qbuf, hbnsim, hbnout, hrel, abuf);
    // 4. qkv GEMM (W-attn)  abuf -> qbuf  [n,128,(h,w)]
    qkv_gemm<<<NB * 49, 256, 0, stream>>>(abuf, wqkv, wbnqkv, qbuf);
    // 5. attn core W: block per (n, p=h); writes bufT region as [b,c,h,w]
    attn_core<1><<<NB * S, 256, 0, stream>>>(qbuf, wbnsim, wbnout, wrel, bufT);
    // 6. conv_up + residual + relu -> d_out
    conv_up_kernel<<<NB * S, 256, 0, stream>>>(bufT, cuw, bn2, x, (float*)d_out);
}

// Round 3
// 376.932 us; speedup vs baseline: 1.3591x; 1.0509x over previous
//
#include <hip/hip_runtime.h>

#define S    56
#define SS   3136        // 56*56
#define CD   64
#define C0   128
#define NB   16
#define EPSF 1e-5f
#define LDW  132         // padded row stride for sq LDS

// ---------------------------------------------------------------------------
// conv_down (128->64) + BN + ReLU.  Block per (b,h).  Standard layout write
// [b,c,h,w] (coalesced).
// ---------------------------------------------------------------------------
__global__ __launch_bounds__(256)
void conv_down_kernel(const float* __restrict__ x, const float* __restrict__ w,
                      const float* __restrict__ bn, float* __restrict__ out)
{
    int bh = blockIdx.x;
    int b = bh / S, h = bh - (bh / S) * S;
    __shared__ float xs[C0][S];
    for (int idx = threadIdx.x; idx < C0 * S; idx += 256) {
        int c = idx / S, wv = idx - (idx / S) * S;
        xs[c][wv] = x[(((size_t)b * C0 + c) * S + h) * S + wv];
    }
    __syncthreads();
    for (int idx = threadIdx.x; idx < CD * S; idx += 256) {
        int o = idx / S, wv = idx - (idx / S) * S;
        const float* wr = w + o * C0;
        float acc = 0.f;
        #pragma unroll 8
        for (int c = 0; c < C0; ++c) acc += wr[c] * xs[c][wv];
        float sc = bn[o] * rsqrtf(bn[3 * CD + o] + EPSF);
        float bi = bn[CD + o] - sc * bn[2 * CD + o];
        float v = sc * acc + bi;
        out[(((size_t)b * CD + o) * S + h) * S + wv] = v > 0.f ? v : 0.f;
    }
}

// ---------------------------------------------------------------------------
// Transpose last two 56x56 dims: in [nc][a][b] -> out [nc][b][a].
// Block per (n*c).  Fully coalesced both sides via LDS tile.
// ---------------------------------------------------------------------------
__global__ __launch_bounds__(256)
void transpose_hw(const float* __restrict__ in, float* __restrict__ out)
{
    __shared__ float t[S][S + 1];
    size_t base = (size_t)blockIdx.x * SS;
    for (int idx = threadIdx.x; idx < SS; idx += 256) {
        int a = idx / S, b = idx - (idx / S) * S;
        t[a][b] = in[base + idx];
    }
    __syncthreads();
    for (int idx = threadIdx.x; idx < SS; idx += 256) {
        int b = idx / S, a = idx - (idx / S) * S;
        out[base + idx] = t[a][b];
    }
}

// ---------------------------------------------------------------------------
// qkv projection GEMM: out[n,o,m] = BN( sum_c w[o,c] * xin[n,c,m] ).
// Spatial-layout agnostic (m flat).  Block: (n, m-tile of 64).
// ---------------------------------------------------------------------------
__global__ __launch_bounds__(256)
void qkv_gemm(const float* __restrict__ xin, const float* __restrict__ w,
              const float* __restrict__ bn, float* __restrict__ out)
{
    __shared__ float wT[64][132];   // [c][o]
    __shared__ float xs[64][68];    // [c][mm]
    int tid = threadIdx.x;
    int n = blockIdx.x / 49, mt = blockIdx.x - (blockIdx.x / 49) * 49;
    int m0 = mt * 64;
    const float* xb = xin + (size_t)n * (CD * SS) + m0;

    for (int idx = tid; idx < 128 * 64; idx += 256) {
        int o = idx >> 6, c = idx & 63;
        wT[c][o] = w[idx];
    }
    for (int idx = tid; idx < 64 * 64; idx += 256) {
        int c = idx >> 6, mm = idx & 63;
        xs[c][mm] = xb[(size_t)c * SS + mm];
    }
    __syncthreads();

    int ty = tid >> 4, tx = tid & 15;
    float acc[8][4];
    #pragma unroll
    for (int r = 0; r < 8; ++r)
        #pragma unroll
        for (int x4 = 0; x4 < 4; ++x4) acc[r][x4] = 0.f;

    #pragma unroll 8
    for (int c = 0; c < 64; ++c) {
        float4 w0 = *(const float4*)&wT[c][ty * 8];
        float4 w1 = *(const float4*)&wT[c][ty * 8 + 4];
        float4 xv = *(const float4*)&xs[c][tx * 4];
        float wr[8] = {w0.x, w0.y, w0.z, w0.w, w1.x, w1.y, w1.z, w1.w};
        float xr[4] = {xv.x, xv.y, xv.z, xv.w};
        #pragma unroll
        for (int r = 0; r < 8; ++r)
            #pragma unroll
            for (int x4 = 0; x4 < 4; ++x4) acc[r][x4] += wr[r] * xr[x4];
    }

    float* ob = out + (size_t)n * (C0 * SS) + m0 + tx * 4;
    #pragma unroll
    for (int r = 0; r < 8; ++r) {
        int o = ty * 8 + r;
        float sc = bn[o] * rsqrtf(bn[384 + o] + EPSF);
        float bi = bn[128 + o] - sc * bn[256 + o];
        float4 res;
        res.x = sc * acc[r][0] + bi;
        res.y = sc * acc[r][1] + bi;
        res.z = sc * acc[r][2] + bi;
        res.w = sc * acc[r][3] + bi;
        *(float4*)&ob[(size_t)o * SS] = res;
    }
}

// ---------------------------------------------------------------------------
// Attention core.  Input qkv: [n][128ch][p][l] (m=(p,l) flat, BN applied).
// Block per (n,p); 4 waves; wave w handles groups w and w+4.
// Lane i owns sim row i entirely in registers.  One barrier total.
// Output write: [n][ch][p][i]  (contiguous in i -> coalesced).
// ---------------------------------------------------------------------------
__global__ __launch_bounds__(256)
void attn_core(const float* __restrict__ qkv,
               const float* __restrict__ bnsim,  // 4 x 24
               const float* __restrict__ bnout,  // 4 x 128
               const float* __restrict__ rel,    // 16 x 111
               float* __restrict__ xout)
{
    __shared__ float  sq[S][LDW];     // [l][ch] transposed stage
    __shared__ float4 srq[112];       // relq: [d] -> 4 q-emb channels
    __shared__ float4 srk[112];       // relk
    __shared__ float4 srv[112][2];    // relv: 8 channels
    __shared__ float  sEv[64], sOd[64], sBs[64];

    int tid = threadIdx.x;
    int n = blockIdx.x / S, p = blockIdx.x - (blockIdx.x / S) * S;
    const float* base = qkv + (size_t)n * (C0 * SS) + (size_t)p * S;

    for (int idx = tid; idx < C0 * S; idx += 256) {
        int ch = idx / S, l = idx - (idx / S) * S;
        sq[l][ch] = base[(size_t)ch * SS + l];
    }
    for (int idx = tid; idx < 16 * 111; idx += 256) {
        int c = idx / 111, d = idx - (idx / 111) * 111;
        float v = rel[idx];
        if (c < 4)       ((float*)&srq[d])[c] = v;
        else if (c < 8)  ((float*)&srk[d])[c - 4] = v;
        else             ((float*)&srv[d][0])[c - 8] = v;
    }
    if (tid < 64) {
        int c0 = tid * 2, c1 = c0 + 1;
        float s0 = bnout[c0] * rsqrtf(bnout[384 + c0] + EPSF);
        float b0 = bnout[128 + c0] - s0 * bnout[256 + c0];
        float s1 = bnout[c1] * rsqrtf(bnout[384 + c1] + EPSF);
        float b1 = bnout[128 + c1] - s1 * bnout[256 + c1];
        sEv[tid] = s0; sOd[tid] = s1; sBs[tid] = b0 + b1;
    }
    __syncthreads();

    int wave = tid >> 6, lane = tid & 63;
    if (lane >= S) return;            // no barriers after this point
    const int i = lane;

    for (int gi = 0; gi < 2; ++gi) {
        int g  = wave + gi * 4;
        int cb = g * 16;

        float s_qk = bnsim[g]      * rsqrtf(bnsim[72 + g] + EPSF);
        float s_qr = bnsim[8 + g]  * rsqrtf(bnsim[80 + g] + EPSF);
        float s_kr = bnsim[16 + g] * rsqrtf(bnsim[88 + g] + EPSF);
        float bsum = (bnsim[24 + g] - s_qk * bnsim[48 + g])
                   + (bnsim[32 + g] - s_qr * bnsim[56 + g])
                   + (bnsim[40 + g] - s_kr * bnsim[64 + g]);

        float4 q = *(const float4*)&sq[i][cb];

        float pr[S];
        #pragma unroll
        for (int j = 0; j < S; ++j) {
            float4 k  = *(const float4*)&sq[j][cb + 4];
            float4 rq = srq[i - j + 55];
            float4 rk = srk[j - i + 55];
            float qk = q.x * k.x  + q.y * k.y  + q.z * k.z  + q.w * k.w;
            float qr = q.x * rq.x + q.y * rq.y + q.z * rq.z + q.w * rq.w;
            float kr = k.x * rk.x + k.y * rk.y + k.z * rk.z + k.w * rk.w;
            pr[j] = s_qk * qk + s_qr * qr + s_kr * kr + bsum;
        }

        // in-lane softmax (4 interleaved chains)
        float m0 = pr[0], m1 = pr[1], m2 = pr[2], m3 = pr[3];
        #pragma unroll
        for (int j = 4; j < S; j += 4) {
            m0 = fmaxf(m0, pr[j]);     m1 = fmaxf(m1, pr[j + 1]);
            m2 = fmaxf(m2, pr[j + 2]); m3 = fmaxf(m3, pr[j + 3]);
        }
        float mm = fmaxf(fmaxf(m0, m1), fmaxf(m2, m3));
        float z0 = 0.f, z1 = 0.f, z2 = 0.f, z3 = 0.f;
        #pragma unroll
        for (int j = 0; j < S; j += 4) {
            pr[j]     = __expf(pr[j]     - mm); z0 += pr[j];
            pr[j + 1] = __expf(pr[j + 1] - mm); z1 += pr[j + 1];
            pr[j + 2] = __expf(pr[j + 2] - mm); z2 += pr[j + 2];
            pr[j + 3] = __expf(pr[j + 3] - mm); z3 += pr[j + 3];
        }
        float inv = 1.f / ((z0 + z1) + (z2 + z3));

        float av[8], ae[8];
        #pragma unroll
        for (int c = 0; c < 8; ++c) { av[c] = 0.f; ae[c] = 0.f; }
        #pragma unroll
        for (int j = 0; j < S; ++j) {
            float sm = pr[j];
            float4 v0 = *(const float4*)&sq[j][cb + 8];
            float4 v1 = *(const float4*)&sq[j][cb + 12];
            float4 r0 = srv[i - j + 55][0];
            float4 r1 = srv[i - j + 55][1];
            av[0] += sm * v0.x; av[1] += sm * v0.y;
            av[2] += sm * v0.z; av[3] += sm * v0.w;
            av[4] += sm * v1.x; av[5] += sm * v1.y;
            av[6] += sm * v1.z; av[7] += sm * v1.w;
            ae[0] += sm * r0.x; ae[1] += sm * r0.y;
            ae[2] += sm * r0.z; ae[3] += sm * r0.w;
            ae[4] += sm * r1.x; ae[5] += sm * r1.y;
            ae[6] += sm * r1.z; ae[7] += sm * r1.w;
        }

        int chb = g * 8;
        #pragma unroll
        for (int c = 0; c < 8; ++c) {
            int ch = chb + c;
            float r = inv * (sEv[ch] * av[c] + sOd[ch] * ae[c]) + sBs[ch];
            xout[(((size_t)n * CD + ch) * S + p) * S + i] = r;
        }
    }
}

// ---------------------------------------------------------------------------
// ReLU + conv_up (64->128) + BN + residual-add + ReLU
// ---------------------------------------------------------------------------
__global__ __launch_bounds__(256)
void conv_up_kernel(const float* __restrict__ xin, const float* __restrict__ w,
                    const float* __restrict__ bn, const float* __restrict__ xres,
                    float* __restrict__ out)
{
    int bh = blockIdx.x;
    int b = bh / S, h = bh - (bh / S) * S;
    __shared__ float xs[CD][S];
    for (int idx = threadIdx.x; idx < CD * S; idx += 256) {
        int c = idx / S, wv = idx - (idx / S) * S;
        float v = xin[(((size_t)b * CD + c) * S + h) * S + wv];
        xs[c][wv] = v > 0.f ? v : 0.f;
    }
    __syncthreads();
    for (int idx = threadIdx.x; idx < C0 * S; idx += 256) {
        int o = idx / S, wv = idx - (idx / S) * S;
        const float* wr = w + o * CD;
        float acc = 0.f;
        #pragma unroll 8
        for (int c = 0; c < CD; ++c) acc += wr[c] * xs[c][wv];
        float sc = bn[o] * rsqrtf(bn[3 * C0 + o] + EPSF);
        float bi = bn[C0 + o] - sc * bn[2 * C0 + o];
        size_t oi = (((size_t)b * C0 + o) * S + h) * S + wv;
        float v = sc * acc + bi + xres[oi];
        out[oi] = v > 0.f ? v : 0.f;
    }
}

extern "C" void kernel_launch(void* const* d_in, const int* in_sizes, int n_in,
                              void* d_out, int out_size, void* d_ws, size_t ws_size,
                              hipStream_t stream)
{
    const float* x      = (const float*)d_in[0];
    const float* cdw    = (const float*)d_in[1];
    const float* bn1    = (const float*)d_in[2];
    const float* hqkv   = (const float*)d_in[3];
    const float* hbnqkv = (const float*)d_in[4];
    const float* hbnsim = (const float*)d_in[5];
    const float* hbnout = (const float*)d_in[6];
    const float* hrel   = (const float*)d_in[7];
    const float* wqkv   = (const float*)d_in[8];
    const float* wbnqkv = (const float*)d_in[9];
    const float* wbnsim = (const float*)d_in[10];
    const float* wbnout = (const float*)d_in[11];
    const float* wrel   = (const float*)d_in[12];
    const float* cuw    = (const float*)d_in[13];
    const float* bn2    = (const float*)d_in[14];

    float* bufA = (float*)d_ws;                 // 16*64*3136
    float* bufB = bufA + (size_t)NB * CD * SS;  // 16*64*3136
    float* qbuf = bufB + (size_t)NB * CD * SS;  // 16*128*3136

    // 1. conv_down -> bufA  [b,c,h,w]
    conv_down_kernel<<<NB * S, 256, 0, stream>>>(x, cdw, bn1, bufA);
    // 2. transpose -> bufB  [b,c,w,h]
    transpose_hw<<<NB * CD, 256, 0, stream>>>(bufA, bufB);
    // 3. qkv GEMM (H)  bufB -> qbuf  [n,128,(w,h)]
    qkv_gemm<<<NB * 49, 256, 0, stream>>>(bufB, hqkv, hbnqkv, qbuf);
    // 4. attn H: p=w, i=h; writes bufA [b,c,w,h]
    attn_core<<<NB * S, 256, 0, stream>>>(qbuf, hbnsim, hbnout, hrel, bufA);
    // 5. transpose -> bufB  [b,c,h,w]
    transpose_hw<<<NB * CD, 256, 0, stream>>>(bufA, bufB);
    // 6. qkv GEMM (W)  bufB -> qbuf  [n,128,(h,w)]
    qkv_gemm<<<NB * 49, 256, 0, stream>>>(bufB, wqkv, wbnqkv, qbuf);
    // 7. attn W: p=h, i=w; writes bufA [b,c,h,w]
    attn_core<<<NB * S, 256, 0, stream>>>(qbuf, wbnsim, wbnout, wrel, bufA);
    // 8. conv_up + residual + relu -> d_out
    conv_up_kernel<<<NB * S, 256, 0, stream>>>(bufA, cuw, bn2, x, (float*)d_out);
}

// Round 4
// 219.710 us; speedup vs baseline: 2.3317x; 1.7156x over previous
//
#include <hip/hip_runtime.h>

#define S    56
#define SS   3136        // 56*56
#define CD   64
#define C0   128
#define NB   16
#define EPSF 1e-5f

typedef __attribute__((ext_vector_type(8))) short short8;
typedef __attribute__((ext_vector_type(4))) float f32x4;
typedef unsigned short ushort_t;

__device__ __forceinline__ ushort_t f2bf(float f) {
    unsigned u = __builtin_bit_cast(unsigned, f);
    unsigned r = u + 0x7FFFu + ((u >> 16) & 1u);
    return (ushort_t)(r >> 16);
}
__device__ __forceinline__ float bf2f(ushort_t u) {
    return __builtin_bit_cast(float, (unsigned)u << 16);
}

// ---------------------------------------------------------------------------
// MFMA GEMM: out[o][m] = BN_o( sum_c w[o][c] * x[c][m] )  (+resid, relus)
// x fp32 [KC][3136] per n; w fp32 [OC][KC]; out fp32 [OC][3136] per n.
// Block = (n, m-tile of 64).  4 waves; wave handles o-tiles wave (+ wave+4).
// B staged transposed bf16 in LDS with 16B XOR swizzle; A loaded from w rows.
// ---------------------------------------------------------------------------
template <int KC, int OC>
__global__ __launch_bounds__(256)
void gemm_mfma(const float* __restrict__ xin, const float* __restrict__ w,
               const float* __restrict__ bn, const float* __restrict__ resid,
               float* __restrict__ out, int relu_in, int relu_out)
{
    constexpr int KSTEPS = KC / 32;
    constexpr int OT     = OC / 64;
    __shared__ char  xT[64 * KC * 2];
    __shared__ float sS[OC], sB[OC];

    int tid = threadIdx.x;
    int n = blockIdx.x / 49, mt = blockIdx.x - (blockIdx.x / 49) * 49;
    int m0 = mt * 64;

    if (tid < OC) {
        float s = bn[tid] * rsqrtf(bn[3 * OC + tid] + EPSF);
        sS[tid] = s;
        sB[tid] = bn[OC + tid] - s * bn[2 * OC + tid];
    }

    int m_l = tid & 63, cq = tid >> 6;
    const float* xb = xin + (size_t)n * KC * SS + m0 + m_l;
    #pragma unroll
    for (int r = 0; r < KSTEPS; ++r) {
        int cbase = cq * 8 + r * 32;
        float v[8];
        #pragma unroll
        for (int u = 0; u < 8; ++u) v[u] = xb[(size_t)(cbase + u) * SS];
        if (relu_in) {
            #pragma unroll
            for (int u = 0; u < 8; ++u) v[u] = fmaxf(v[u], 0.f);
        }
        short8 sv;
        #pragma unroll
        for (int u = 0; u < 8; ++u) ((ushort_t*)&sv)[u] = f2bf(v[u]);
        *(short8*)(xT + m_l * (KC * 2) + ((cbase * 2) ^ ((m_l & 7) << 4))) = sv;
    }
    __syncthreads();

    int wave = tid >> 6, lane = tid & 63;
    int lo = lane & 15, hi = lane >> 4;

    // A fragments from w (fp32 -> bf16), reused across all m-subtiles
    short8 afrag[OT][KSTEPS];
    #pragma unroll
    for (int ot = 0; ot < OT; ++ot) {
        int o = (wave + ot * 4) * 16 + lo;
        #pragma unroll
        for (int ks = 0; ks < KSTEPS; ++ks) {
            const float* wr = w + (size_t)o * KC + ks * 32 + hi * 8;
            short8 a;
            #pragma unroll
            for (int u = 0; u < 8; ++u) ((ushort_t*)&a)[u] = f2bf(wr[u]);
            afrag[ot][ks] = a;
        }
    }

    f32x4 acc[OT][4];
    #pragma unroll
    for (int ot = 0; ot < OT; ++ot)
        #pragma unroll
        for (int ms = 0; ms < 4; ++ms)
            acc[ot][ms] = (f32x4){0.f, 0.f, 0.f, 0.f};

    #pragma unroll
    for (int ms = 0; ms < 4; ++ms) {
        int m_loc = ms * 16 + lo;
        #pragma unroll
        for (int ks = 0; ks < KSTEPS; ++ks) {
            short8 b = *(const short8*)(xT + m_loc * (KC * 2) +
                        (((ks * 32 + hi * 8) * 2) ^ ((m_loc & 7) << 4)));
            #pragma unroll
            for (int ot = 0; ot < OT; ++ot)
                acc[ot][ms] = __builtin_amdgcn_mfma_f32_16x16x32_bf16(
                                  afrag[ot][ks], b, acc[ot][ms], 0, 0, 0);
        }
    }

    #pragma unroll
    for (int ot = 0; ot < OT; ++ot) {
        int o_base = (wave + ot * 4) * 16;
        #pragma unroll
        for (int ms = 0; ms < 4; ++ms) {
            #pragma unroll
            for (int r = 0; r < 4; ++r) {
                int o = o_base + hi * 4 + r;
                int m = m0 + ms * 16 + lo;
                float val = acc[ot][ms][r] * sS[o] + sB[o];
                if (resid) val += resid[((size_t)n * OC + o) * SS + m];
                if (relu_out) val = fmaxf(val, 0.f);
                out[((size_t)n * OC + o) * SS + m] = val;
            }
        }
    }
}

// ---------------------------------------------------------------------------
// Transpose last two 56x56 dims: in [nc][a][b] -> out [nc][b][a].
// ---------------------------------------------------------------------------
__global__ __launch_bounds__(256)
void transpose_hw(const float* __restrict__ in, float* __restrict__ out)
{
    __shared__ float t[S][S + 1];
    size_t base = (size_t)blockIdx.x * SS;
    for (int idx = threadIdx.x; idx < SS; idx += 256) {
        int a = idx / S, b = idx - (idx / S) * S;
        t[a][b] = in[base + idx];
    }
    __syncthreads();
    for (int idx = threadIdx.x; idx < SS; idx += 256) {
        int b = idx / S, a = idx - (idx / S) * S;
        out[base + idx] = t[a][b];
    }
}

// ---------------------------------------------------------------------------
// Attention core, online-softmax, 2-group-fused, bf16-packed LDS.
// Input qkv fp32 [n][128][p][l] (BN applied).  Block per (n,p); 4 waves;
// wave w handles groups w and w+4 simultaneously; lane i owns row i.
// Output write: [n][ch][p][i] (contiguous in i).
// ---------------------------------------------------------------------------
__global__ __launch_bounds__(256)
void attn_core(const float* __restrict__ qkv,
               const float* __restrict__ bnsim,  // 4 x 24
               const float* __restrict__ bnout,  // 4 x 128
               const float* __restrict__ rel,    // 16 x 111
               float* __restrict__ xout)
{
    __shared__ float    sqq[S][36];        // q fp32: [l][g*4+c]
    __shared__ ushort_t kpk[S][4][8];      // [l][wavepair]{g=w c0..3, g=w+4 c0..3}
    __shared__ ushort_t vpk[S][4][16];     // [l][wavepair]{g=w c0..7, g=w+4 c0..7}
    __shared__ ushort_t rqk[112][8];       // {qemb[0..3][d], kemb[0..3][110-d]}
    __shared__ ushort_t rvv[112][8];       // {vemb[0..7][d]}
    __shared__ float    sEv[64], sOd[64], sBs[64];

    int tid = threadIdx.x;
    int n = blockIdx.x / S, p = blockIdx.x - (blockIdx.x / S) * S;
    const float* base = qkv + (size_t)n * (C0 * SS) + (size_t)p * S;

    for (int idx = tid; idx < C0 * S; idx += 256) {
        int o = idx / S, l = idx - (idx / S) * S;
        float v = base[(size_t)o * SS + l];
        int g = o >> 4, part = o & 15, wp = g & 3, hi4 = g >> 2;
        if (part < 4)       sqq[l][g * 4 + part] = v;
        else if (part < 8)  kpk[l][wp][(part - 4) + hi4 * 4] = f2bf(v);
        else                vpk[l][wp][(part - 8) + hi4 * 8] = f2bf(v);
    }
    for (int idx = tid; idx < 16 * 111; idx += 256) {
        int c = idx / 111, d = idx - (idx / 111) * 111;
        float v = rel[idx];
        if (c < 4)      rqk[d][c] = f2bf(v);
        else if (c < 8) rqk[110 - d][c] = f2bf(v);   // reversed k-emb
        else            rvv[d][c - 8] = f2bf(v);
    }
    if (tid < 64) {
        int c0 = tid * 2, c1 = c0 + 1;
        float s0 = bnout[c0] * rsqrtf(bnout[384 + c0] + EPSF);
        float b0 = bnout[128 + c0] - s0 * bnout[256 + c0];
        float s1 = bnout[c1] * rsqrtf(bnout[384 + c1] + EPSF);
        float b1 = bnout[128 + c1] - s1 * bnout[256 + c1];
        sEv[tid] = s0; sOd[tid] = s1; sBs[tid] = b0 + b1;
    }
    __syncthreads();

    int wave = tid >> 6, lane = tid & 63;
    if (lane >= S) return;                 // no barriers below
    const int i = lane;
    const int g0 = wave, g1 = wave + 4;

    float sqk0 = bnsim[g0]      * rsqrtf(bnsim[72 + g0] + EPSF);
    float sqr0 = bnsim[8 + g0]  * rsqrtf(bnsim[80 + g0] + EPSF);
    float skr0 = bnsim[16 + g0] * rsqrtf(bnsim[88 + g0] + EPSF);
    float bs0  = (bnsim[24 + g0] - sqk0 * bnsim[48 + g0])
               + (bnsim[32 + g0] - sqr0 * bnsim[56 + g0])
               + (bnsim[40 + g0] - skr0 * bnsim[64 + g0]);
    float sqk1 = bnsim[g1]      * rsqrtf(bnsim[72 + g1] + EPSF);
    float sqr1 = bnsim[8 + g1]  * rsqrtf(bnsim[80 + g1] + EPSF);
    float skr1 = bnsim[16 + g1] * rsqrtf(bnsim[88 + g1] + EPSF);
    float bs1  = (bnsim[24 + g1] - sqk1 * bnsim[48 + g1])
               + (bnsim[32 + g1] - sqr1 * bnsim[56 + g1])
               + (bnsim[40 + g1] - skr1 * bnsim[64 + g1]);

    float4 q0 = *(const float4*)&sqq[i][g0 * 4];
    float4 q1 = *(const float4*)&sqq[i][g1 * 4];

    float mr0 = -3e38f, mr1 = -3e38f, Z0 = 0.f, Z1 = 0.f;
    float av0[8], ae0[8], av1[8], ae1[8];
    #pragma unroll
    for (int c = 0; c < 8; ++c) { av0[c]=0.f; ae0[c]=0.f; av1[c]=0.f; ae1[c]=0.f; }

    for (int c4 = 0; c4 < 7; ++c4) {
        int j0 = c4 * 8;
        float pc0[8], pc1[8];
        #pragma unroll
        for (int u = 0; u < 8; ++u) {
            int j = j0 + u;
            short8 kk = *(const short8*)&kpk[j][wave][0];
            short8 rr = *(const short8*)&rqk[i - j + 55][0];
            const ushort_t* kp = (const ushort_t*)&kk;
            const ushort_t* rp = (const ushort_t*)&rr;
            float k00=bf2f(kp[0]), k01=bf2f(kp[1]), k02=bf2f(kp[2]), k03=bf2f(kp[3]);
            float k10=bf2f(kp[4]), k11=bf2f(kp[5]), k12=bf2f(kp[6]), k13=bf2f(kp[7]);
            float rq0=bf2f(rp[0]), rq1=bf2f(rp[1]), rq2=bf2f(rp[2]), rq3=bf2f(rp[3]);
            float rk0=bf2f(rp[4]), rk1=bf2f(rp[5]), rk2=bf2f(rp[6]), rk3=bf2f(rp[7]);
            float qk_0 = q0.x*k00 + q0.y*k01 + q0.z*k02 + q0.w*k03;
            float qr_0 = q0.x*rq0 + q0.y*rq1 + q0.z*rq2 + q0.w*rq3;
            float kr_0 = k00*rk0 + k01*rk1 + k02*rk2 + k03*rk3;
            pc0[u] = sqk0*qk_0 + sqr0*qr_0 + skr0*kr_0 + bs0;
            float qk_1 = q1.x*k10 + q1.y*k11 + q1.z*k12 + q1.w*k13;
            float qr_1 = q1.x*rq0 + q1.y*rq1 + q1.z*rq2 + q1.w*rq3;
            float kr_1 = k10*rk0 + k11*rk1 + k12*rk2 + k13*rk3;
            pc1[u] = sqk1*qk_1 + sqr1*qr_1 + skr1*kr_1 + bs1;
        }
        // online-softmax update, group 0
        float cm0 = fmaxf(fmaxf(fmaxf(pc0[0],pc0[1]),fmaxf(pc0[2],pc0[3])),
                          fmaxf(fmaxf(pc0[4],pc0[5]),fmaxf(pc0[6],pc0[7])));
        float nm0 = fmaxf(mr0, cm0);
        float sc0 = __expf(mr0 - nm0);
        mr0 = nm0; Z0 *= sc0;
        #pragma unroll
        for (int c = 0; c < 8; ++c) { av0[c]*=sc0; ae0[c]*=sc0; }
        #pragma unroll
        for (int u = 0; u < 8; ++u) { pc0[u] = __expf(pc0[u]-mr0); Z0 += pc0[u]; }
        // group 1
        float cm1 = fmaxf(fmaxf(fmaxf(pc1[0],pc1[1]),fmaxf(pc1[2],pc1[3])),
                          fmaxf(fmaxf(pc1[4],pc1[5]),fmaxf(pc1[6],pc1[7])));
        float nm1 = fmaxf(mr1, cm1);
        float sc1 = __expf(mr1 - nm1);
        mr1 = nm1; Z1 *= sc1;
        #pragma unroll
        for (int c = 0; c < 8; ++c) { av1[c]*=sc1; ae1[c]*=sc1; }
        #pragma unroll
        for (int u = 0; u < 8; ++u) { pc1[u] = __expf(pc1[u]-mr1); Z1 += pc1[u]; }
        // PV accumulate
        #pragma unroll
        for (int u = 0; u < 8; ++u) {
            int j = j0 + u;
            short8 va = *(const short8*)&vpk[j][wave][0];
            short8 vb = *(const short8*)&vpk[j][wave][8];
            short8 rv = *(const short8*)&rvv[i - j + 55][0];
            const ushort_t* ap = (const ushort_t*)&va;
            const ushort_t* bp = (const ushort_t*)&vb;
            const ushort_t* vp = (const ushort_t*)&rv;
            float p0 = pc0[u], p1 = pc1[u];
            #pragma unroll
            for (int c = 0; c < 8; ++c) {
                float rvf = bf2f(vp[c]);
                av0[c] += p0 * bf2f(ap[c]);
                av1[c] += p1 * bf2f(bp[c]);
                ae0[c] += p0 * rvf;
                ae1[c] += p1 * rvf;
            }
        }
    }

    float inv0 = 1.f / Z0, inv1 = 1.f / Z1;
    size_t obase = (size_t)n * (CD * SS) + (size_t)p * S + i;
    #pragma unroll
    for (int c = 0; c < 8; ++c) {
        int ch = g0 * 8 + c;
        xout[obase + (size_t)ch * SS] =
            inv0 * (sEv[ch] * av0[c] + sOd[ch] * ae0[c]) + sBs[ch];
    }
    #pragma unroll
    for (int c = 0; c < 8; ++c) {
        int ch = g1 * 8 + c;
        xout[obase + (size_t)ch * SS] =
            inv1 * (sEv[ch] * av1[c] + sOd[ch] * ae1[c]) + sBs[ch];
    }
}

extern "C" void kernel_launch(void* const* d_in, const int* in_sizes, int n_in,
                              void* d_out, int out_size, void* d_ws, size_t ws_size,
                              hipStream_t stream)
{
    const float* x      = (const float*)d_in[0];
    const float* cdw    = (const float*)d_in[1];
    const float* bn1    = (const float*)d_in[2];
    const float* hqkv   = (const float*)d_in[3];
    const float* hbnqkv = (const float*)d_in[4];
    const float* hbnsim = (const float*)d_in[5];
    const float* hbnout = (const float*)d_in[6];
    const float* hrel   = (const float*)d_in[7];
    const float* wqkv   = (const float*)d_in[8];
    const float* wbnqkv = (const float*)d_in[9];
    const float* wbnsim = (const float*)d_in[10];
    const float* wbnout = (const float*)d_in[11];
    const float* wrel   = (const float*)d_in[12];
    const float* cuw    = (const float*)d_in[13];
    const float* bn2    = (const float*)d_in[14];

    float* bufA = (float*)d_ws;                 // 16*64*3136
    float* bufB = bufA + (size_t)NB * CD * SS;  // 16*64*3136
    float* qbuf = bufB + (size_t)NB * CD * SS;  // 16*128*3136

    // 1. conv_down (MFMA) + BN + ReLU -> bufA [b,c,(h,w)]
    gemm_mfma<128, 64><<<NB * 49, 256, 0, stream>>>(x, cdw, bn1, nullptr, bufA, 0, 1);
    // 2. transpose -> bufB [b,c,(w,h)]
    transpose_hw<<<NB * CD, 256, 0, stream>>>(bufA, bufB);
    // 3. qkv GEMM (H) -> qbuf
    gemm_mfma<64, 128><<<NB * 49, 256, 0, stream>>>(bufB, hqkv, hbnqkv, nullptr, qbuf, 0, 0);
    // 4. attn H: p=w, i=h -> bufA [b,c,w,h]
    attn_core<<<NB * S, 256, 0, stream>>>(qbuf, hbnsim, hbnout, hrel, bufA);
    // 5. transpose -> bufB [b,c,(h,w)]
    transpose_hw<<<NB * CD, 256, 0, stream>>>(bufA, bufB);
    // 6. qkv GEMM (W) -> qbuf
    gemm_mfma<64, 128><<<NB * 49, 256, 0, stream>>>(bufB, wqkv, wbnqkv, nullptr, qbuf, 0, 0);
    // 7. attn W: p=h, i=w -> bufA [b,c,h,w]
    attn_core<<<NB * S, 256, 0, stream>>>(qbuf, wbnsim, wbnout, wrel, bufA);
    // 8. ReLU-in + conv_up (MFMA) + BN + resid + ReLU -> d_out
    gemm_mfma<64, 128><<<NB * 49, 256, 0, stream>>>(bufA, cuw, bn2, x, (float*)d_out, 1, 1);
}

// Round 5
// 173.933 us; speedup vs baseline: 2.9454x; 1.2632x over previous
//
#include <hip/hip_runtime.h>

#define S    56
#define SS   3136        // 56*56
#define CD   64
#define C0   128
#define NB   16
#define EPSF 1e-5f
#define L2E  1.44269504088896f

typedef __attribute__((ext_vector_type(8))) short short8;
typedef __attribute__((ext_vector_type(4))) float f32x4;
typedef __attribute__((ext_vector_type(2))) float f32x2;
typedef unsigned short ushort_t;

__device__ __forceinline__ ushort_t f2bf(float f) {
    unsigned u = __builtin_bit_cast(unsigned, f);
    unsigned r = u + 0x7FFFu + ((u >> 16) & 1u);
    return (ushort_t)(r >> 16);
}
__device__ __forceinline__ float bf2f(ushort_t u) {
    return __builtin_bit_cast(float, (unsigned)u << 16);
}
__device__ __forceinline__ f32x2 pkfma(f32x2 a, f32x2 b, f32x2 c) {
    return __builtin_elementwise_fma(a, b, c);
}
__device__ __forceinline__ f32x2 pkmax(f32x2 a, f32x2 b) {
    return __builtin_elementwise_max(a, b);
}
__device__ __forceinline__ f32x2 splat2(float v) { return (f32x2){v, v}; }

#if __has_builtin(__builtin_amdgcn_exp2f)
#define EXP2F __builtin_amdgcn_exp2f
#else
#define EXP2F exp2f
#endif

// ---------------------------------------------------------------------------
// MFMA GEMM (conv_down / conv_up): out[o][m] = BN(sum_c w[o][c]*x[c][m])
// ---------------------------------------------------------------------------
template <int KC, int OC>
__global__ __launch_bounds__(256)
void gemm_mfma(const float* __restrict__ xin, const float* __restrict__ w,
               const float* __restrict__ bn, const float* __restrict__ resid,
               float* __restrict__ out, int relu_in, int relu_out)
{
    constexpr int KSTEPS = KC / 32;
    constexpr int OT     = OC / 64;
    __shared__ char  xT[64 * KC * 2];
    __shared__ float sS[OC], sB[OC];

    int tid = threadIdx.x;
    int n = blockIdx.x / 49, mt = blockIdx.x - (blockIdx.x / 49) * 49;
    int m0 = mt * 64;

    if (tid < OC) {
        float s = bn[tid] * rsqrtf(bn[3 * OC + tid] + EPSF);
        sS[tid] = s;
        sB[tid] = bn[OC + tid] - s * bn[2 * OC + tid];
    }

    int m_l = tid & 63, cq = tid >> 6;
    const float* xb = xin + (size_t)n * KC * SS + m0 + m_l;
    #pragma unroll
    for (int r = 0; r < KSTEPS; ++r) {
        int cbase = cq * 8 + r * 32;
        float v[8];
        #pragma unroll
        for (int u = 0; u < 8; ++u) v[u] = xb[(size_t)(cbase + u) * SS];
        if (relu_in) {
            #pragma unroll
            for (int u = 0; u < 8; ++u) v[u] = fmaxf(v[u], 0.f);
        }
        short8 sv;
        #pragma unroll
        for (int u = 0; u < 8; ++u) ((ushort_t*)&sv)[u] = f2bf(v[u]);
        *(short8*)(xT + m_l * (KC * 2) + ((cbase * 2) ^ ((m_l & 7) << 4))) = sv;
    }
    __syncthreads();

    int wave = tid >> 6, lane = tid & 63;
    int lo = lane & 15, hi = lane >> 4;

    short8 afrag[OT][KSTEPS];
    #pragma unroll
    for (int ot = 0; ot < OT; ++ot) {
        int o = (wave + ot * 4) * 16 + lo;
        #pragma unroll
        for (int ks = 0; ks < KSTEPS; ++ks) {
            const float* wr = w + (size_t)o * KC + ks * 32 + hi * 8;
            short8 a;
            #pragma unroll
            for (int u = 0; u < 8; ++u) ((ushort_t*)&a)[u] = f2bf(wr[u]);
            afrag[ot][ks] = a;
        }
    }

    f32x4 acc[OT][4];
    #pragma unroll
    for (int ot = 0; ot < OT; ++ot)
        #pragma unroll
        for (int ms = 0; ms < 4; ++ms)
            acc[ot][ms] = (f32x4){0.f, 0.f, 0.f, 0.f};

    #pragma unroll
    for (int ms = 0; ms < 4; ++ms) {
        int m_loc = ms * 16 + lo;
        #pragma unroll
        for (int ks = 0; ks < KSTEPS; ++ks) {
            short8 b = *(const short8*)(xT + m_loc * (KC * 2) +
                        (((ks * 32 + hi * 8) * 2) ^ ((m_loc & 7) << 4)));
            #pragma unroll
            for (int ot = 0; ot < OT; ++ot)
                acc[ot][ms] = __builtin_amdgcn_mfma_f32_16x16x32_bf16(
                                  afrag[ot][ks], b, acc[ot][ms], 0, 0, 0);
        }
    }

    #pragma unroll
    for (int ot = 0; ot < OT; ++ot) {
        int o_base = (wave + ot * 4) * 16;
        #pragma unroll
        for (int ms = 0; ms < 4; ++ms) {
            #pragma unroll
            for (int r = 0; r < 4; ++r) {
                int o = o_base + hi * 4 + r;
                int m = m0 + ms * 16 + lo;
                float val = acc[ot][ms][r] * sS[o] + sB[o];
                if (resid) val += resid[((size_t)n * OC + o) * SS + m];
                if (relu_out) val = fmaxf(val, 0.f);
                out[((size_t)n * OC + o) * SS + m] = val;
            }
        }
    }
}

// ---------------------------------------------------------------------------
// qkv GEMM: KC=64 -> OC=128 with BN folded.  q channels (x foldq = s_qk*log2e)
// -> qpack[n][32][m]; k/v channels -> kvpack[n*3136 + m][96] via LDS tile:
//   k slot = (g&3)*8  + c*2 + (g>>2)      (c = part-4, 0..3)
//   v slot = 32 + (g&3)*16 + c*2 + (g>>2) (c = part-8, 0..7)
// ---------------------------------------------------------------------------
__global__ __launch_bounds__(256)
void qkv_gemm_mfma(const float* __restrict__ xin, const float* __restrict__ w,
                   const float* __restrict__ bn, const float* __restrict__ bnsim,
                   float* __restrict__ qpack, float* __restrict__ kvpack)
{
    constexpr int KC = 64, OC = 128;
    __shared__ char  xT[64 * KC * 2];
    __shared__ float sS[OC], sB[OC];
    __shared__ float kvtile[64][96];
    __shared__ float foldq[8];

    int tid = threadIdx.x;
    int n = blockIdx.x / 49, mt = blockIdx.x - (blockIdx.x / 49) * 49;
    int m0 = mt * 64;

    if (tid < OC) {
        float s = bn[tid] * rsqrtf(bn[3 * OC + tid] + EPSF);
        sS[tid] = s;
        sB[tid] = bn[OC + tid] - s * bn[2 * OC + tid];
    }
    if (tid < 8) foldq[tid] = bnsim[tid] * rsqrtf(bnsim[72 + tid] + EPSF) * L2E;

    int m_l = tid & 63, cq = tid >> 6;
    const float* xb = xin + (size_t)n * KC * SS + m0 + m_l;
    #pragma unroll
    for (int r = 0; r < 2; ++r) {
        int cbase = cq * 8 + r * 32;
        short8 sv;
        #pragma unroll
        for (int u = 0; u < 8; ++u)
            ((ushort_t*)&sv)[u] = f2bf(xb[(size_t)(cbase + u) * SS]);
        *(short8*)(xT + m_l * (KC * 2) + ((cbase * 2) ^ ((m_l & 7) << 4))) = sv;
    }
    __syncthreads();

    int wave = tid >> 6, lane = tid & 63;
    int lo = lane & 15, hi = lane >> 4;

    short8 afrag[2][2];
    #pragma unroll
    for (int ot = 0; ot < 2; ++ot) {
        int o = (wave + ot * 4) * 16 + lo;
        #pragma unroll
        for (int ks = 0; ks < 2; ++ks) {
            const float* wr = w + (size_t)o * KC + ks * 32 + hi * 8;
            short8 a;
            #pragma unroll
            for (int u = 0; u < 8; ++u) ((ushort_t*)&a)[u] = f2bf(wr[u]);
            afrag[ot][ks] = a;
        }
    }

    f32x4 acc[2][4];
    #pragma unroll
    for (int ot = 0; ot < 2; ++ot)
        #pragma unroll
        for (int ms = 0; ms < 4; ++ms)
            acc[ot][ms] = (f32x4){0.f, 0.f, 0.f, 0.f};

    #pragma unroll
    for (int ms = 0; ms < 4; ++ms) {
        int m_loc = ms * 16 + lo;
        #pragma unroll
        for (int ks = 0; ks < 2; ++ks) {
            short8 b = *(const short8*)(xT + m_loc * (KC * 2) +
                        (((ks * 32 + hi * 8) * 2) ^ ((m_loc & 7) << 4)));
            #pragma unroll
            for (int ot = 0; ot < 2; ++ot)
                acc[ot][ms] = __builtin_amdgcn_mfma_f32_16x16x32_bf16(
                                  afrag[ot][ks], b, acc[ot][ms], 0, 0, 0);
        }
    }

    #pragma unroll
    for (int ot = 0; ot < 2; ++ot) {
        int o_base = (wave + ot * 4) * 16;
        #pragma unroll
        for (int ms = 0; ms < 4; ++ms) {
            int m_loc = ms * 16 + lo;
            #pragma unroll
            for (int r = 0; r < 4; ++r) {
                int o = o_base + hi * 4 + r;
                float val = acc[ot][ms][r] * sS[o] + sB[o];
                int g = o >> 4, part = o & 15;
                if (part < 4) {
                    qpack[((size_t)n * 32 + g * 4 + part) * SS + m0 + m_loc] =
                        val * foldq[g];
                } else if (part < 8) {
                    kvtile[m_loc][(g & 3) * 8 + (part - 4) * 2 + (g >> 2)] = val;
                } else {
                    kvtile[m_loc][32 + (g & 3) * 16 + (part - 8) * 2 + (g >> 2)] = val;
                }
            }
        }
    }
    __syncthreads();
    float4* kvout = (float4*)(kvpack + ((size_t)n * SS + m0) * 96);
    const float4* kvt = (const float4*)&kvtile[0][0];
    for (int idx = tid; idx < 64 * 96 / 4; idx += 256) kvout[idx] = kvt[idx];
}

// ---------------------------------------------------------------------------
// Transpose last two 56x56 dims.
// ---------------------------------------------------------------------------
__global__ __launch_bounds__(256)
void transpose_hw(const float* __restrict__ in, float* __restrict__ out)
{
    __shared__ float t[S][S + 1];
    size_t base = (size_t)blockIdx.x * SS;
    for (int idx = threadIdx.x; idx < SS; idx += 256) {
        int a = idx / S, b = idx - (idx / S) * S;
        t[a][b] = in[base + idx];
    }
    __syncthreads();
    for (int idx = threadIdx.x; idx < SS; idx += 256) {
        int b = idx / S, a = idx - (idx / S) * S;
        out[base + idx] = t[a][b];
    }
}

// ---------------------------------------------------------------------------
// Attention core v3.  Q from qpack (pre-scaled by s_qk*log2e), K/V from
// kvpack via wave-uniform scalar loads, rel bf16 in LDS, packed-f32 group
// pairs (g, g+4), exp2-domain online softmax with deferred rescale.
// Block per (n,p); wave w -> groups (w, w+4); lane i owns output row i.
// ---------------------------------------------------------------------------
__global__ __launch_bounds__(256)
void attn_core(const float* __restrict__ qpack,
               const float* __restrict__ kvpack,
               const float* __restrict__ bnsim,  // 4 x 24
               const float* __restrict__ bnout,  // 4 x 128
               const float* __restrict__ rel,    // 16 x 111
               float* __restrict__ xout)
{
    __shared__ float    sqp[64][34];     // [l][pair-col]; rows >=56 zero
    __shared__ ushort_t rqk[120][8];     // {qemb[c][d], kemb[c][110-d]}
    __shared__ ushort_t rvv[120][8];     // {vemb[c][d]}

    int tid = threadIdx.x;
    int n = blockIdx.x / S, p = blockIdx.x - (blockIdx.x / S) * S;

    // zero LDS (pad rows must be benign)
    for (int idx = tid; idx < 64 * 34; idx += 256) ((float*)sqp)[idx] = 0.f;
    for (int idx = tid; idx < 120 * 8 / 2; idx += 256) {
        ((unsigned*)rqk)[idx] = 0u;
        ((unsigned*)rvv)[idx] = 0u;
    }
    __syncthreads();

    // stage q (pre-scaled), pair layout: col = ((g&3)*4 + c)*2 + (g>>2)
    const float* qb = qpack + (size_t)n * 32 * SS + (size_t)p * S;
    for (int idx = tid; idx < 32 * S; idx += 256) {
        int qc = idx / S, l = idx - (idx / S) * S;
        int g = qc >> 2, c = qc & 3;
        sqp[l][((g & 3) * 4 + c) * 2 + (g >> 2)] = qb[(size_t)qc * SS + l];
    }
    // stage rel bf16 (kemb reversed)
    for (int idx = tid; idx < 16 * 111; idx += 256) {
        int c = idx / 111, d = idx - (idx / 111) * 111;
        float v = rel[idx];
        if (c < 4)      rqk[d][c] = f2bf(v);
        else if (c < 8) rqk[110 - d][c] = f2bf(v);
        else            rvv[d][c - 8] = f2bf(v);
    }
    __syncthreads();

    const int wv = __builtin_amdgcn_readfirstlane(tid >> 6);
    const int i  = tid & 63;
    const int g0 = wv, g1 = wv + 4;

    // per-wave combine coefficients (uniform scalar math)
    float sqk0 = bnsim[g0] * rsqrtf(bnsim[72 + g0] + EPSF);
    float sqr0 = bnsim[8 + g0] * rsqrtf(bnsim[80 + g0] + EPSF);
    float skr0 = bnsim[16 + g0] * rsqrtf(bnsim[88 + g0] + EPSF);
    float bsm0 = (bnsim[24 + g0] - sqk0 * bnsim[48 + g0])
               + (bnsim[32 + g0] - sqr0 * bnsim[56 + g0])
               + (bnsim[40 + g0] - skr0 * bnsim[64 + g0]);
    float sqk1 = bnsim[g1] * rsqrtf(bnsim[72 + g1] + EPSF);
    float sqr1 = bnsim[8 + g1] * rsqrtf(bnsim[80 + g1] + EPSF);
    float skr1 = bnsim[16 + g1] * rsqrtf(bnsim[88 + g1] + EPSF);
    float bsm1 = (bnsim[24 + g1] - sqk1 * bnsim[48 + g1])
               + (bnsim[32 + g1] - sqr1 * bnsim[56 + g1])
               + (bnsim[40 + g1] - skr1 * bnsim[64 + g1]);
    f32x2 cqr2 = {sqr0 / sqk0, sqr1 / sqk1};       // qr acc carries L*s_qk
    f32x2 ckr2 = {skr0 * L2E,  skr1 * L2E};
    f32x2 bs2  = {bsm0 * L2E,  bsm1 * L2E};

    f32x2 q2[4];
    #pragma unroll
    for (int c = 0; c < 4; ++c)
        q2[c] = *(const f32x2*)&sqp[i][(wv * 4 + c) * 2];

    const float* kvb = kvpack + ((size_t)n * SS + (size_t)p * S) * 96;

    f32x2 mr2 = splat2(-3e38f), Z2 = splat2(0.f);
    f32x2 av2[8], ae2[8];
    #pragma unroll
    for (int c = 0; c < 8; ++c) { av2[c] = splat2(0.f); ae2[c] = splat2(0.f); }

    for (int c8 = 0; c8 < 7; ++c8) {
        const int j0 = c8 * 8;
        const float* krow = kvb + j0 * 96 + wv * 8;
        f32x2 pc2[8];
        #pragma unroll
        for (int u = 0; u < 8; ++u) {
            const float* kj = krow + u * 96;
            short8 rr = *(const short8*)&rqk[i - (j0 + u) + 55][0];
            f32x2 qk2 = splat2(0.f), qr2 = splat2(0.f), kr2 = splat2(0.f);
            #pragma unroll
            for (int c = 0; c < 4; ++c) {
                f32x2 k2 = *(const f32x2*)(kj + c * 2);
                qk2 = pkfma(q2[c], k2, qk2);
                qr2 = pkfma(q2[c], splat2(bf2f(((const ushort_t*)&rr)[c])), qr2);
                kr2 = pkfma(k2,    splat2(bf2f(((const ushort_t*)&rr)[4 + c])), kr2);
            }
            pc2[u] = qk2 + pkfma(cqr2, qr2, pkfma(ckr2, kr2, bs2));
        }
        // deferred online-softmax (log2 domain)
        f32x2 cm2 = pc2[0];
        #pragma unroll
        for (int u = 1; u < 8; ++u) cm2 = pkmax(cm2, pc2[u]);
        f32x2 nm2 = pkmax(mr2, cm2);
        float dm = fmaxf(nm2.x - mr2.x, nm2.y - mr2.y);
        if (!__all(dm <= 12.0f)) {
            f32x2 sc2;
            sc2.x = EXP2F(mr2.x - nm2.x);
            sc2.y = EXP2F(mr2.y - nm2.y);
            mr2 = nm2;
            Z2 *= sc2;
            #pragma unroll
            for (int c = 0; c < 8; ++c) { av2[c] *= sc2; ae2[c] *= sc2; }
        }
        const float* vrow = kvb + j0 * 96 + 32 + wv * 16;
        #pragma unroll
        for (int u = 0; u < 8; ++u) {
            f32x2 e2;
            e2.x = EXP2F(pc2[u].x - mr2.x);
            e2.y = EXP2F(pc2[u].y - mr2.y);
            Z2 += e2;
            const float* vj = vrow + u * 96;
            short8 rv = *(const short8*)&rvv[i - (j0 + u) + 55][0];
            #pragma unroll
            for (int c = 0; c < 8; ++c) {
                av2[c] = pkfma(e2, *(const f32x2*)(vj + c * 2), av2[c]);
                ae2[c] = pkfma(e2, splat2(bf2f(((const ushort_t*)&rv)[c])), ae2[c]);
            }
        }
    }

    if (i < S) {
        f32x2 inv2 = {1.f / Z2.x, 1.f / Z2.y};
        size_t ob = (size_t)n * (CD * SS) + (size_t)p * S + i;
        #pragma unroll
        for (int c = 0; c < 8; ++c) {
            int ch0 = wv * 8 + c, ch1 = ch0 + 32;
            int oa = ch0 * 2, obq = ch1 * 2;
            float se0 = bnout[oa] * rsqrtf(bnout[384 + oa] + EPSF);
            float be0 = bnout[128 + oa] - se0 * bnout[256 + oa];
            float so0 = bnout[oa + 1] * rsqrtf(bnout[384 + oa + 1] + EPSF);
            float bo0 = bnout[128 + oa + 1] - so0 * bnout[256 + oa + 1];
            float se1 = bnout[obq] * rsqrtf(bnout[384 + obq] + EPSF);
            float be1 = bnout[128 + obq] - se1 * bnout[256 + obq];
            float so1 = bnout[obq + 1] * rsqrtf(bnout[384 + obq + 1] + EPSF);
            float bo1 = bnout[128 + obq + 1] - so1 * bnout[256 + obq + 1];
            xout[ob + (size_t)ch0 * SS] =
                inv2.x * (se0 * av2[c].x + so0 * ae2[c].x) + (be0 + bo0);
            xout[ob + (size_t)ch1 * SS] =
                inv2.y * (se1 * av2[c].y + so1 * ae2[c].y) + (be1 + bo1);
        }
    }
}

extern "C" void kernel_launch(void* const* d_in, const int* in_sizes, int n_in,
                              void* d_out, int out_size, void* d_ws, size_t ws_size,
                              hipStream_t stream)
{
    const float* x      = (const float*)d_in[0];
    const float* cdw    = (const float*)d_in[1];
    const float* bn1    = (const float*)d_in[2];
    const float* hqkv   = (const float*)d_in[3];
    const float* hbnqkv = (const float*)d_in[4];
    const float* hbnsim = (const float*)d_in[5];
    const float* hbnout = (const float*)d_in[6];
    const float* hrel   = (const float*)d_in[7];
    const float* wqkv   = (const float*)d_in[8];
    const float* wbnqkv = (const float*)d_in[9];
    const float* wbnsim = (const float*)d_in[10];
    const float* wbnout = (const float*)d_in[11];
    const float* wrel   = (const float*)d_in[12];
    const float* cuw    = (const float*)d_in[13];
    const float* bn2    = (const float*)d_in[14];

    float* bufA   = (float*)d_ws;                        // 16*64*3136
    float* bufB   = bufA + (size_t)NB * CD * SS;         // 16*64*3136
    float* qpack  = bufB + (size_t)NB * CD * SS;         // 16*32*3136
    float* kvpack = qpack + (size_t)NB * 32 * SS;        // 16*3136*96

    // 1. conv_down + BN + ReLU -> bufA [b,c,(h,w)]
    gemm_mfma<128, 64><<<NB * 49, 256, 0, stream>>>(x, cdw, bn1, nullptr, bufA, 0, 1);
    // 2. transpose -> bufB [b,c,(w,h)]
    transpose_hw<<<NB * CD, 256, 0, stream>>>(bufA, bufB);
    // 3. qkv GEMM (H) -> qpack, kvpack
    qkv_gemm_mfma<<<NB * 49, 256, 0, stream>>>(bufB, hqkv, hbnqkv, hbnsim, qpack, kvpack);
    // 4. attn H: p=w, i=h -> bufA [b,c,w,h]
    attn_core<<<NB * S, 256, 0, stream>>>(qpack, kvpack, hbnsim, hbnout, hrel, bufA);
    // 5. transpose -> bufB [b,c,(h,w)]
    transpose_hw<<<NB * CD, 256, 0, stream>>>(bufA, bufB);
    // 6. qkv GEMM (W) -> qpack, kvpack
    qkv_gemm_mfma<<<NB * 49, 256, 0, stream>>>(bufB, wqkv, wbnqkv, wbnsim, qpack, kvpack);
    // 7. attn W: p=h, i=w -> bufA [b,c,h,w]
    attn_core<<<NB * S, 256, 0, stream>>>(qpack, kvpack, wbnsim, wbnout, wrel, bufA);
    // 8. ReLU-in + conv_up + BN + resid + ReLU -> d_out
    gemm_mfma<64, 128><<<NB * 49, 256, 0, stream>>>(bufA, cuw, bn2, x, (float*)d_out, 1, 1);
}